// Round 1
// baseline (1760.788 us; speedup 1.0000x reference)
//
#include <hip/hip_runtime.h>
#include <math.h>

#define LQ 2048
#define DMODEL 3072
#define NHEADS 24
#define DHEADC 128
#define NQKV 9216
#define NOUT1 21504
#define KIN2 15360
#define EPSV 1e-6f

typedef __attribute__((ext_vector_type(8))) short short8;
typedef __attribute__((ext_vector_type(4))) short short4v;
typedef __attribute__((ext_vector_type(4))) float f32x4;

__device__ __forceinline__ short f2bf(float f) {
  unsigned int u = __float_as_uint(f);
  unsigned int r = (u + 0x7fffu + ((u >> 16) & 1u)) >> 16;
  return (short)(unsigned short)r;
}

__device__ __forceinline__ float geluf(float v) {
  float inner = 0.7978845608028654f * (v + 0.044715f * v * v * v);
  return 0.5f * v * (1.0f + tanhf(inner));
}

// ---------------- fp32 (K,N) -> bf16 (N,K) transpose+convert ----------------
__global__ __launch_bounds__(256) void k_wconv(const float* __restrict__ w,
                                               short* __restrict__ wt,
                                               int K, int N) {
  __shared__ float tile[32][33];
  int bk = blockIdx.x * 32, bn = blockIdx.y * 32;
  int t = threadIdx.x;
  int r = t >> 3, c = (t & 7) * 4;
  float4 v = *reinterpret_cast<const float4*>(w + (size_t)(bk + r) * N + bn + c);
  tile[r][c + 0] = v.x; tile[r][c + 1] = v.y; tile[r][c + 2] = v.z; tile[r][c + 3] = v.w;
  __syncthreads();
  short4v o;
  o[0] = f2bf(tile[c + 0][r]); o[1] = f2bf(tile[c + 1][r]);
  o[2] = f2bf(tile[c + 2][r]); o[3] = f2bf(tile[c + 3][r]);
  *reinterpret_cast<short4v*>(wt + (size_t)(bn + r) * K + bk + c) = o;
}

// ---------------- mod = silu(vec) @ mod_w  (split-K GEMV) ----------------
__global__ __launch_bounds__(256) void k_modpart(const float* __restrict__ vec,
                                                 const float* __restrict__ mod_w,
                                                 float* __restrict__ partial) {
  __shared__ float sv[128];
  int t = threadIdx.x;
  int nb = blockIdx.x * 256;
  int kb = blockIdx.y * 128;
  if (t < 128) { float z = vec[kb + t]; sv[t] = z / (1.0f + expf(-z)); }
  __syncthreads();
  const float* wp = mod_w + (size_t)kb * NQKV + nb + t;
  float acc = 0.0f;
#pragma unroll 8
  for (int k = 0; k < 128; k++) acc += sv[k] * wp[(size_t)k * NQKV];
  partial[(size_t)blockIdx.y * NQKV + nb + t] = acc;
}

__global__ __launch_bounds__(256) void k_modred(const float* __restrict__ partial,
                                                const float* __restrict__ mod_b,
                                                float* __restrict__ modv) {
  int n = blockIdx.x * 256 + threadIdx.x;
  float acc = mod_b[n];
#pragma unroll
  for (int ky = 0; ky < 24; ky++) acc += partial[(size_t)ky * NQKV + n];
  modv[n] = acc;
}

// ---------------- LayerNorm + (1+scale)*xn + shift -> bf16 ----------------
__global__ __launch_bounds__(256) void k_ln(const float* __restrict__ x,
                                            const float* __restrict__ modv,
                                            short* __restrict__ xmod) {
  int l = blockIdx.x, t = threadIdx.x;
  const float* xr = x + (size_t)l * DMODEL;
  const float4* xr4 = (const float4*)xr;
  float4 vbuf[3];
  float s = 0.f, ss = 0.f;
#pragma unroll
  for (int i = 0; i < 3; i++) {
    float4 v = xr4[t + i * 256];
    vbuf[i] = v;
    s += v.x + v.y + v.z + v.w;
    ss += v.x * v.x + v.y * v.y + v.z * v.z + v.w * v.w;
  }
#pragma unroll
  for (int m = 32; m >= 1; m >>= 1) { s += __shfl_xor(s, m); ss += __shfl_xor(ss, m); }
  __shared__ float red[8];
  __shared__ float stats[2];
  int wave = t >> 6;
  if ((t & 63) == 0) { red[wave] = s; red[4 + wave] = ss; }
  __syncthreads();
  if (t == 0) {
    float st = red[0] + red[1] + red[2] + red[3];
    float sst = red[4] + red[5] + red[6] + red[7];
    float mu = st / DMODEL;
    float var = sst / DMODEL - mu * mu;
    stats[0] = mu; stats[1] = rsqrtf(var + EPSV);
  }
  __syncthreads();
  float mu = stats[0], rr = stats[1];
#pragma unroll
  for (int i = 0; i < 3; i++) {
    float4 v = vbuf[i];
    int c = (t + i * 256) * 4;
    short4v o;
    o[0] = f2bf((1.f + modv[DMODEL + c + 0]) * ((v.x - mu) * rr) + modv[c + 0]);
    o[1] = f2bf((1.f + modv[DMODEL + c + 1]) * ((v.y - mu) * rr) + modv[c + 1]);
    o[2] = f2bf((1.f + modv[DMODEL + c + 2]) * ((v.z - mu) * rr) + modv[c + 2]);
    o[3] = f2bf((1.f + modv[DMODEL + c + 3]) * ((v.w - mu) * rr) + modv[c + 3]);
    *(short4v*)(xmod + (size_t)l * DMODEL + c) = o;
  }
}

// ---------------- GEMM1: xmod(2048x3072) @ W1t(21504x3072)^T ----------------
// 128x128 tile, BK=32, 4 waves (2x2), 16x16x32 bf16 MFMA, fused qkv/mlp scatter.
__global__ __launch_bounds__(256) void k_gemm1(const short* __restrict__ A,
                                               const short* __restrict__ Bt,
                                               const float* __restrict__ bias,
                                               float* __restrict__ qraw,
                                               float* __restrict__ kraw,
                                               short* __restrict__ vt,
                                               short* __restrict__ a2) {
  __shared__ short As[128][40];
  __shared__ short Bs[128][40];
  const int K = DMODEL;
  int t = threadIdx.x;
  int bm = blockIdx.x * 128, bn = blockIdx.y * 128;
  int wave = t >> 6, lane = t & 63;
  int wm = (wave >> 1) * 64, wn = (wave & 1) * 64;
  int lrow = lane & 15, lko = (lane >> 4) * 8;
  int sr = t >> 2, sc = (t & 3) * 8;
  const short* pa0 = A + (size_t)(bm + sr) * K + sc;
  const short* pa1 = A + (size_t)(bm + sr + 64) * K + sc;
  const short* pb0 = Bt + (size_t)(bn + sr) * K + sc;
  const short* pb1 = Bt + (size_t)(bn + sr + 64) * K + sc;
  f32x4 zero = {0.f, 0.f, 0.f, 0.f};
  f32x4 acc[4][4];
#pragma unroll
  for (int i = 0; i < 4; i++)
#pragma unroll
    for (int j = 0; j < 4; j++) acc[i][j] = zero;
  short8 ra0 = *(const short8*)pa0, ra1 = *(const short8*)pa1;
  short8 rb0 = *(const short8*)pb0, rb1 = *(const short8*)pb1;
  for (int k0 = 0; k0 < K; k0 += 32) {
    __syncthreads();
    *(short8*)&As[sr][sc] = ra0; *(short8*)&As[sr + 64][sc] = ra1;
    *(short8*)&Bs[sr][sc] = rb0; *(short8*)&Bs[sr + 64][sc] = rb1;
    __syncthreads();
    if (k0 + 32 < K) {
      ra0 = *(const short8*)(pa0 + k0 + 32); ra1 = *(const short8*)(pa1 + k0 + 32);
      rb0 = *(const short8*)(pb0 + k0 + 32); rb1 = *(const short8*)(pb1 + k0 + 32);
    }
    short8 af[4], bfr[4];
#pragma unroll
    for (int i = 0; i < 4; i++) af[i] = *(const short8*)&As[wm + i * 16 + lrow][lko];
#pragma unroll
    for (int j = 0; j < 4; j++) bfr[j] = *(const short8*)&Bs[wn + j * 16 + lrow][lko];
#pragma unroll
    for (int i = 0; i < 4; i++)
#pragma unroll
      for (int j = 0; j < 4; j++)
        acc[i][j] = __builtin_amdgcn_mfma_f32_16x16x32_bf16(af[i], bfr[j], acc[i][j], 0, 0, 0);
  }
  int r0 = bm + wm + ((lane >> 4) << 2);
  int c0 = bn + wn + lrow;
#pragma unroll
  for (int j = 0; j < 4; j++) {
    int col = c0 + j * 16;
    float bb = bias[col];
#pragma unroll
    for (int i = 0; i < 4; i++) {
#pragma unroll
      for (int r = 0; r < 4; r++) {
        float v = acc[i][j][r] + bb;
        int row = r0 + i * 16 + r;
        if (col < NQKV) {
          int s = col / DMODEL;
          int rem = col - s * DMODEL;
          int hh = rem >> 7, d = rem & 127;
          if (s == 0)      qraw[((size_t)hh * LQ + row) * DHEADC + d] = v;
          else if (s == 1) kraw[((size_t)hh * LQ + row) * DHEADC + d] = v;
          else             vt[((size_t)hh * DHEADC + d) * LQ + row] = f2bf(v);
        } else {
          a2[(size_t)row * KIN2 + DMODEL + (col - NQKV)] = f2bf(geluf(v));
        }
      }
    }
  }
}

// ---------------- RMSnorm + RoPE for q,k -> bf16 [h][l][d] ----------------
__global__ __launch_bounds__(256) void k_qkprep(const float* __restrict__ qraw,
                                                const float* __restrict__ kraw,
                                                const float* __restrict__ pe,
                                                const float* __restrict__ q_scale,
                                                const float* __restrict__ k_scale,
                                                short* __restrict__ qn,
                                                short* __restrict__ kn) {
  int wave = threadIdx.x >> 6, lane = threadIdx.x & 63;
  int l = blockIdx.x * 4 + wave;
  int h = blockIdx.y;
  int isK = blockIdx.z;
  const float* src = (isK ? kraw : qraw) + ((size_t)h * LQ + l) * DHEADC;
  const float* sc  = isK ? k_scale : q_scale;
  short* dst = (isK ? kn : qn) + ((size_t)h * LQ + l) * DHEADC;
  float2 tv = *(const float2*)(src + lane * 2);
  float ssq = tv.x * tv.x + tv.y * tv.y;
#pragma unroll
  for (int m = 1; m < 64; m <<= 1) ssq += __shfl_xor(ssq, m);
  float rr = rsqrtf(ssq * (1.0f / 128.0f) + EPSV);
  float t0 = tv.x * rr * sc[lane * 2];
  float t1 = tv.y * rr * sc[lane * 2 + 1];
  float4 p4 = *(const float4*)(pe + ((size_t)l * 64 + lane) * 4);
  float o0 = p4.x * t0 + p4.y * t1;
  float o1 = p4.z * t0 + p4.w * t1;
  if (!isK) { o0 *= 0.08838834764831845f; o1 *= 0.08838834764831845f; }  // 1/sqrt(128)
  dst[lane * 2] = f2bf(o0);
  dst[lane * 2 + 1] = f2bf(o1);
}

// ---------------- Flash attention: block = (head, 128 q rows) ----------------
__global__ __launch_bounds__(256) void k_flash(const short* __restrict__ qn,
                                               const short* __restrict__ kn,
                                               const short* __restrict__ vt,
                                               short* __restrict__ a2) {
  __shared__ short Qs[128][136];
  __shared__ short Ks[32][136];
  __shared__ short Vs[128][40];
  __shared__ short Ps[4][32][40];
  int t = threadIdx.x;
  int qb = blockIdx.x * 128, h = blockIdx.y;
  int wave = t >> 6, lane = t & 63;
  int lrow = lane & 15, lko = (lane >> 4) * 8;
  int wm = wave * 32;
  const short* qbase = qn + ((size_t)h * LQ + qb) * DHEADC;
#pragma unroll
  for (int i = 0; i < 8; i++) {
    int idx = i * 256 + t;
    int row = idx >> 4, c = (idx & 15) * 8;
    *(short8*)&Qs[row][c] = *(const short8*)(qbase + (size_t)row * DHEADC + c);
  }
  f32x4 zero = {0.f, 0.f, 0.f, 0.f};
  f32x4 oacc[2][8];
#pragma unroll
  for (int i = 0; i < 2; i++)
#pragma unroll
    for (int j = 0; j < 8; j++) oacc[i][j] = zero;
  float mI[2][4], lI[2][4];
#pragma unroll
  for (int i = 0; i < 2; i++)
#pragma unroll
    for (int r = 0; r < 4; r++) { mI[i][r] = -1e30f; lI[i][r] = 0.f; }
  __syncthreads();
  for (int kt = 0; kt < 64; kt++) {
    int krow0 = kt * 32;
#pragma unroll
    for (int i = 0; i < 2; i++) {
      int idx = i * 256 + t;
      int row = idx >> 4, c = (idx & 15) * 8;
      *(short8*)&Ks[row][c] = *(const short8*)(kn + ((size_t)h * LQ + krow0 + row) * DHEADC + c);
    }
#pragma unroll
    for (int i = 0; i < 2; i++) {
      int idx = i * 256 + t;
      int d = idx >> 2, c = (idx & 3) * 8;
      *(short8*)&Vs[d][c] = *(const short8*)(vt + ((size_t)h * DHEADC + d) * LQ + krow0 + c);
    }
    __syncthreads();
    f32x4 sacc[2][2];
#pragma unroll
    for (int i = 0; i < 2; i++)
#pragma unroll
      for (int j = 0; j < 2; j++) sacc[i][j] = zero;
#pragma unroll
    for (int kk = 0; kk < 4; kk++) {
      short8 qa[2], kb[2];
#pragma unroll
      for (int i = 0; i < 2; i++) qa[i] = *(const short8*)&Qs[wm + i * 16 + lrow][kk * 32 + lko];
#pragma unroll
      for (int j = 0; j < 2; j++) kb[j] = *(const short8*)&Ks[j * 16 + lrow][kk * 32 + lko];
#pragma unroll
      for (int i = 0; i < 2; i++)
#pragma unroll
        for (int j = 0; j < 2; j++)
          sacc[i][j] = __builtin_amdgcn_mfma_f32_16x16x32_bf16(qa[i], kb[j], sacc[i][j], 0, 0, 0);
    }
    // online softmax (rows live in (lane>>4, reg); reduce across lane&15)
#pragma unroll
    for (int i = 0; i < 2; i++) {
      float al[4];
#pragma unroll
      for (int r = 0; r < 4; r++) {
        float mx = fmaxf(sacc[i][0][r], sacc[i][1][r]);
#pragma unroll
        for (int m = 1; m < 16; m <<= 1) mx = fmaxf(mx, __shfl_xor(mx, m));
        float mnew = fmaxf(mI[i][r], mx);
        float alpha = exp2f((mI[i][r] - mnew) * 1.4426950408889634f);
        float p0 = exp2f((sacc[i][0][r] - mnew) * 1.4426950408889634f);
        float p1 = exp2f((sacc[i][1][r] - mnew) * 1.4426950408889634f);
        sacc[i][0][r] = p0; sacc[i][1][r] = p1;
        float rs = p0 + p1;
#pragma unroll
        for (int m = 1; m < 16; m <<= 1) rs += __shfl_xor(rs, m);
        lI[i][r] = lI[i][r] * alpha + rs;
        mI[i][r] = mnew;
        al[r] = alpha;
      }
#pragma unroll
      for (int j = 0; j < 8; j++) {
        f32x4 o = oacc[i][j];
        o[0] *= al[0]; o[1] *= al[1]; o[2] *= al[2]; o[3] *= al[3];
        oacc[i][j] = o;
      }
      // P: C/D layout -> LDS (transpose to A-operand layout)
#pragma unroll
      for (int j = 0; j < 2; j++)
#pragma unroll
        for (int r = 0; r < 4; r++)
          Ps[wave][i * 16 + (lane >> 4) * 4 + r][j * 16 + lrow] = f2bf(sacc[i][j][r]);
    }
    short8 pa[2];
#pragma unroll
    for (int i = 0; i < 2; i++) pa[i] = *(const short8*)&Ps[wave][i * 16 + lrow][lko];
#pragma unroll
    for (int j = 0; j < 8; j++) {
      short8 vb = *(const short8*)&Vs[j * 16 + lrow][lko];
#pragma unroll
      for (int i = 0; i < 2; i++)
        oacc[i][j] = __builtin_amdgcn_mfma_f32_16x16x32_bf16(pa[i], vb, oacc[i][j], 0, 0, 0);
    }
    __syncthreads();
  }
#pragma unroll
  for (int i = 0; i < 2; i++) {
    float inv[4];
#pragma unroll
    for (int r = 0; r < 4; r++) inv[r] = 1.0f / lI[i][r];
#pragma unroll
    for (int j = 0; j < 8; j++) {
#pragma unroll
      for (int r = 0; r < 4; r++) {
        int row = qb + wm + i * 16 + (lane >> 4) * 4 + r;
        int col = h * DHEADC + j * 16 + lrow;
        a2[(size_t)row * KIN2 + col] = f2bf(oacc[i][j][r] * inv[r]);
      }
    }
  }
}

// ---------------- GEMM2: a2(2048x15360) @ W2t(3072x15360)^T, fused residual ----------------
__global__ __launch_bounds__(256) void k_gemm2(const short* __restrict__ A,
                                               const short* __restrict__ Bt,
                                               const float* __restrict__ bias,
                                               const float* __restrict__ x,
                                               const float* __restrict__ gate,
                                               float* __restrict__ out) {
  __shared__ short As[128][40];
  __shared__ short Bs[128][40];
  const int K = KIN2;
  int t = threadIdx.x;
  int bm = blockIdx.x * 128, bn = blockIdx.y * 128;
  int wave = t >> 6, lane = t & 63;
  int wm = (wave >> 1) * 64, wn = (wave & 1) * 64;
  int lrow = lane & 15, lko = (lane >> 4) * 8;
  int sr = t >> 2, sc = (t & 3) * 8;
  const short* pa0 = A + (size_t)(bm + sr) * K + sc;
  const short* pa1 = A + (size_t)(bm + sr + 64) * K + sc;
  const short* pb0 = Bt + (size_t)(bn + sr) * K + sc;
  const short* pb1 = Bt + (size_t)(bn + sr + 64) * K + sc;
  f32x4 zero = {0.f, 0.f, 0.f, 0.f};
  f32x4 acc[4][4];
#pragma unroll
  for (int i = 0; i < 4; i++)
#pragma unroll
    for (int j = 0; j < 4; j++) acc[i][j] = zero;
  short8 ra0 = *(const short8*)pa0, ra1 = *(const short8*)pa1;
  short8 rb0 = *(const short8*)pb0, rb1 = *(const short8*)pb1;
  for (int k0 = 0; k0 < K; k0 += 32) {
    __syncthreads();
    *(short8*)&As[sr][sc] = ra0; *(short8*)&As[sr + 64][sc] = ra1;
    *(short8*)&Bs[sr][sc] = rb0; *(short8*)&Bs[sr + 64][sc] = rb1;
    __syncthreads();
    if (k0 + 32 < K) {
      ra0 = *(const short8*)(pa0 + k0 + 32); ra1 = *(const short8*)(pa1 + k0 + 32);
      rb0 = *(const short8*)(pb0 + k0 + 32); rb1 = *(const short8*)(pb1 + k0 + 32);
    }
    short8 af[4], bfr[4];
#pragma unroll
    for (int i = 0; i < 4; i++) af[i] = *(const short8*)&As[wm + i * 16 + lrow][lko];
#pragma unroll
    for (int j = 0; j < 4; j++) bfr[j] = *(const short8*)&Bs[wn + j * 16 + lrow][lko];
#pragma unroll
    for (int i = 0; i < 4; i++)
#pragma unroll
      for (int j = 0; j < 4; j++)
        acc[i][j] = __builtin_amdgcn_mfma_f32_16x16x32_bf16(af[i], bfr[j], acc[i][j], 0, 0, 0);
  }
  int r0 = bm + wm + ((lane >> 4) << 2);
  int c0 = bn + wn + lrow;
#pragma unroll
  for (int j = 0; j < 4; j++) {
    int col = c0 + j * 16;
    float bb = bias[col];
    float g = gate[col];
#pragma unroll
    for (int i = 0; i < 4; i++) {
#pragma unroll
      for (int r = 0; r < 4; r++) {
        int row = r0 + i * 16 + r;
        float v = acc[i][j][r] + bb;
        out[(size_t)row * DMODEL + col] = x[(size_t)row * DMODEL + col] + g * v;
      }
    }
  }
}

extern "C" void kernel_launch(void* const* d_in, const int* in_sizes, int n_in,
                              void* d_out, int out_size, void* d_ws, size_t ws_size,
                              hipStream_t stream) {
  (void)in_sizes; (void)n_in; (void)out_size; (void)ws_size;
  const float* x       = (const float*)d_in[0];
  const float* vec     = (const float*)d_in[1];
  const float* pe      = (const float*)d_in[2];
  const float* mod_w   = (const float*)d_in[3];
  const float* mod_b   = (const float*)d_in[4];
  const float* lin1_w  = (const float*)d_in[5];
  const float* lin1_b  = (const float*)d_in[6];
  const float* lin2_w  = (const float*)d_in[7];
  const float* lin2_b  = (const float*)d_in[8];
  const float* q_scale = (const float*)d_in[9];
  const float* k_scale = (const float*)d_in[10];
  float* out = (float*)d_out;

  // workspace carve (~283 MiB total; W2t reuses W1t region after GEMM1)
  char* base = (char*)d_ws;
  size_t off = 0;
  auto carve = [&](size_t bytes) -> void* {
    void* q = base + off;
    off += (bytes + 255) & ~(size_t)255;
    return q;
  };
  short* W1t  = (short*)carve((size_t)NOUT1 * DMODEL * 2);      // also W2t later
  short* xmod = (short*)carve((size_t)LQ * DMODEL * 2);
  float* qraw = (float*)carve((size_t)NHEADS * LQ * DHEADC * 4);
  float* kraw = (float*)carve((size_t)NHEADS * LQ * DHEADC * 4);
  short* qnb  = (short*)carve((size_t)NHEADS * LQ * DHEADC * 2);
  short* knb  = (short*)carve((size_t)NHEADS * LQ * DHEADC * 2);
  short* vtb  = (short*)carve((size_t)NHEADS * LQ * DHEADC * 2);
  short* a2   = (short*)carve((size_t)LQ * KIN2 * 2);
  float* modv = (float*)carve((size_t)NQKV * 4);
  float* part = (float*)carve((size_t)24 * NQKV * 4);

  k_wconv<<<dim3(DMODEL / 32, NOUT1 / 32), 256, 0, stream>>>(lin1_w, W1t, DMODEL, NOUT1);
  k_modpart<<<dim3(NQKV / 256, 24), 256, 0, stream>>>(vec, mod_w, part);
  k_modred<<<NQKV / 256, 256, 0, stream>>>(part, mod_b, modv);
  k_ln<<<LQ, 256, 0, stream>>>(x, modv, xmod);
  k_gemm1<<<dim3(LQ / 128, NOUT1 / 128), 256, 0, stream>>>(xmod, W1t, lin1_b, qraw, kraw, vtb, a2);
  k_wconv<<<dim3(KIN2 / 32, DMODEL / 32), 256, 0, stream>>>(lin2_w, W1t, KIN2, DMODEL);
  k_qkprep<<<dim3(LQ / 4, NHEADS, 2), 256, 0, stream>>>(qraw, kraw, pe, q_scale, k_scale, qnb, knb);
  k_flash<<<dim3(LQ / 128, NHEADS), 256, 0, stream>>>(qnb, knb, vtb, a2);
  k_gemm2<<<dim3(LQ / 128, DMODEL / 128), 256, 0, stream>>>(a2, W1t, lin2_b, x, modv + 2 * DMODEL, out);
}

// Round 2
// 1697.838 us; speedup vs baseline: 1.0371x; 1.0371x over previous
//
#include <hip/hip_runtime.h>
#include <math.h>

#define LQ 2048
#define DMODEL 3072
#define NHEADS 24
#define DHEADC 128
#define NQKV 9216
#define NOUT1 21504
#define KIN2 15360
#define EPSV 1e-6f

typedef __attribute__((ext_vector_type(8))) short short8;
typedef __attribute__((ext_vector_type(4))) short short4v;
typedef __attribute__((ext_vector_type(4))) float f32x4;

__device__ __forceinline__ short f2bf(float f) {
  unsigned int u = __float_as_uint(f);
  unsigned int r = (u + 0x7fffu + ((u >> 16) & 1u)) >> 16;
  return (short)(unsigned short)r;
}

__device__ __forceinline__ float geluf(float v) {
  float inner = 0.7978845608028654f * (v + 0.044715f * v * v * v);
  return 0.5f * v * (1.0f + tanhf(inner));
}

// async global->LDS DMA, 16 B per lane; LDS dst = base + lane*16 (wave-uniform base)
__device__ __forceinline__ void async_ld16(void* lds, const void* g) {
  __builtin_amdgcn_global_load_lds(
      (const __attribute__((address_space(1))) unsigned int*)g,
      (__attribute__((address_space(3))) unsigned int*)lds, 16, 0, 0);
}

// ---------------- fp32 (K,N) -> bf16 (N,K) transpose+convert ----------------
__global__ __launch_bounds__(256) void k_wconv(const float* __restrict__ w,
                                               short* __restrict__ wt,
                                               int K, int N) {
  __shared__ float tile[32][33];
  int bk = blockIdx.x * 32, bn = blockIdx.y * 32;
  int t = threadIdx.x;
  int r = t >> 3, c = (t & 7) * 4;
  float4 v = *reinterpret_cast<const float4*>(w + (size_t)(bk + r) * N + bn + c);
  tile[r][c + 0] = v.x; tile[r][c + 1] = v.y; tile[r][c + 2] = v.z; tile[r][c + 3] = v.w;
  __syncthreads();
  short4v o;
  o[0] = f2bf(tile[c + 0][r]); o[1] = f2bf(tile[c + 1][r]);
  o[2] = f2bf(tile[c + 2][r]); o[3] = f2bf(tile[c + 3][r]);
  *reinterpret_cast<short4v*>(wt + (size_t)(bn + r) * K + bk + c) = o;
}

// ---------------- mod = silu(vec) @ mod_w  (split-K GEMV) ----------------
__global__ __launch_bounds__(256) void k_modpart(const float* __restrict__ vec,
                                                 const float* __restrict__ mod_w,
                                                 float* __restrict__ partial) {
  __shared__ float sv[128];
  int t = threadIdx.x;
  int nb = blockIdx.x * 256;
  int kb = blockIdx.y * 128;
  if (t < 128) { float z = vec[kb + t]; sv[t] = z / (1.0f + expf(-z)); }
  __syncthreads();
  const float* wp = mod_w + (size_t)kb * NQKV + nb + t;
  float acc = 0.0f;
#pragma unroll 8
  for (int k = 0; k < 128; k++) acc += sv[k] * wp[(size_t)k * NQKV];
  partial[(size_t)blockIdx.y * NQKV + nb + t] = acc;
}

__global__ __launch_bounds__(256) void k_modred(const float* __restrict__ partial,
                                                const float* __restrict__ mod_b,
                                                float* __restrict__ modv) {
  int n = blockIdx.x * 256 + threadIdx.x;
  float acc = mod_b[n];
#pragma unroll
  for (int ky = 0; ky < 24; ky++) acc += partial[(size_t)ky * NQKV + n];
  modv[n] = acc;
}

// ---------------- LayerNorm + (1+scale)*xn + shift -> bf16 ----------------
__global__ __launch_bounds__(256) void k_ln(const float* __restrict__ x,
                                            const float* __restrict__ modv,
                                            short* __restrict__ xmod) {
  int l = blockIdx.x, t = threadIdx.x;
  const float* xr = x + (size_t)l * DMODEL;
  const float4* xr4 = (const float4*)xr;
  float4 vbuf[3];
  float s = 0.f, ss = 0.f;
#pragma unroll
  for (int i = 0; i < 3; i++) {
    float4 v = xr4[t + i * 256];
    vbuf[i] = v;
    s += v.x + v.y + v.z + v.w;
    ss += v.x * v.x + v.y * v.y + v.z * v.z + v.w * v.w;
  }
#pragma unroll
  for (int m = 32; m >= 1; m >>= 1) { s += __shfl_xor(s, m); ss += __shfl_xor(ss, m); }
  __shared__ float red[8];
  __shared__ float stats[2];
  int wave = t >> 6;
  if ((t & 63) == 0) { red[wave] = s; red[4 + wave] = ss; }
  __syncthreads();
  if (t == 0) {
    float st = red[0] + red[1] + red[2] + red[3];
    float sst = red[4] + red[5] + red[6] + red[7];
    float mu = st / DMODEL;
    float var = sst / DMODEL - mu * mu;
    stats[0] = mu; stats[1] = rsqrtf(var + EPSV);
  }
  __syncthreads();
  float mu = stats[0], rr = stats[1];
#pragma unroll
  for (int i = 0; i < 3; i++) {
    float4 v = vbuf[i];
    int c = (t + i * 256) * 4;
    short4v o;
    o[0] = f2bf((1.f + modv[DMODEL + c + 0]) * ((v.x - mu) * rr) + modv[c + 0]);
    o[1] = f2bf((1.f + modv[DMODEL + c + 1]) * ((v.y - mu) * rr) + modv[c + 1]);
    o[2] = f2bf((1.f + modv[DMODEL + c + 2]) * ((v.z - mu) * rr) + modv[c + 2]);
    o[3] = f2bf((1.f + modv[DMODEL + c + 3]) * ((v.w - mu) * rr) + modv[c + 3]);
    *(short4v*)(xmod + (size_t)l * DMODEL + c) = o;
  }
}

// ---------------- GEMM1: xmod(2048x3072) @ W1t(21504x3072)^T ----------------
// m97 structure: 128x128 tile, BK=32, global_load_lds dwordx4, unpadded [128][32].
__global__ __launch_bounds__(256) void k_gemm1(const short* __restrict__ A,
                                               const short* __restrict__ Bt,
                                               const float* __restrict__ bias,
                                               float* __restrict__ qraw,
                                               float* __restrict__ kraw,
                                               short* __restrict__ vt,
                                               short* __restrict__ a2) {
  __shared__ __align__(16) short As[128 * 32];
  __shared__ __align__(16) short Bs[128 * 32];
  const int K = DMODEL;
  int t = threadIdx.x;
  int bm = blockIdx.x * 128, bn = blockIdx.y * 128;
  int wave = t >> 6, lane = t & 63;
  int wm = (wave >> 1) * 64, wn = (wave & 1) * 64;
  int lrow = lane & 15, lko = (lane >> 4) * 8;
  // staging: lane covers row (lane>>2) of a 16-row group, bytes (lane&3)*16
  int srow = wave * 16 + (lane >> 2);
  int scol = (lane & 3) * 8;
  const short* ga0 = A + (size_t)(bm + srow) * K + scol;
  const short* ga1 = ga0 + (size_t)64 * K;
  const short* gb0 = Bt + (size_t)(bn + srow) * K + scol;
  const short* gb1 = gb0 + (size_t)64 * K;
  short* la0 = As + wave * 512;
  short* la1 = As + 64 * 32 + wave * 512;
  short* lb0 = Bs + wave * 512;
  short* lb1 = Bs + 64 * 32 + wave * 512;
  f32x4 zero = {0.f, 0.f, 0.f, 0.f};
  f32x4 acc[4][4];
#pragma unroll
  for (int i = 0; i < 4; i++)
#pragma unroll
    for (int j = 0; j < 4; j++) acc[i][j] = zero;
  for (int k0 = 0; k0 < K; k0 += 32) {
    __syncthreads();
    async_ld16(la0, ga0 + k0);
    async_ld16(la1, ga1 + k0);
    async_ld16(lb0, gb0 + k0);
    async_ld16(lb1, gb1 + k0);
    __syncthreads();
    short8 af[4], bfr[4];
#pragma unroll
    for (int i = 0; i < 4; i++) af[i] = *(const short8*)&As[(wm + i * 16 + lrow) * 32 + lko];
#pragma unroll
    for (int j = 0; j < 4; j++) bfr[j] = *(const short8*)&Bs[(wn + j * 16 + lrow) * 32 + lko];
#pragma unroll
    for (int i = 0; i < 4; i++)
#pragma unroll
      for (int j = 0; j < 4; j++)
        acc[i][j] = __builtin_amdgcn_mfma_f32_16x16x32_bf16(af[i], bfr[j], acc[i][j], 0, 0, 0);
  }
  int r0 = bm + wm + ((lane >> 4) << 2);
  int c0 = bn + wn + lrow;
#pragma unroll
  for (int j = 0; j < 4; j++) {
    int col = c0 + j * 16;
    float bb = bias[col];
#pragma unroll
    for (int i = 0; i < 4; i++) {
#pragma unroll
      for (int r = 0; r < 4; r++) {
        float v = acc[i][j][r] + bb;
        int row = r0 + i * 16 + r;
        if (col < NQKV) {
          int s = col / DMODEL;
          int rem = col - s * DMODEL;
          int hh = rem >> 7, d = rem & 127;
          if (s == 0)      qraw[((size_t)hh * LQ + row) * DHEADC + d] = v;
          else if (s == 1) kraw[((size_t)hh * LQ + row) * DHEADC + d] = v;
          else             vt[((size_t)hh * DHEADC + d) * LQ + row] = f2bf(v);
        } else {
          a2[(size_t)row * KIN2 + DMODEL + (col - NQKV)] = f2bf(geluf(v));
        }
      }
    }
  }
}

// ---------------- RMSnorm + RoPE for q,k -> bf16 [h][l][d] ----------------
__global__ __launch_bounds__(256) void k_qkprep(const float* __restrict__ qraw,
                                                const float* __restrict__ kraw,
                                                const float* __restrict__ pe,
                                                const float* __restrict__ q_scale,
                                                const float* __restrict__ k_scale,
                                                short* __restrict__ qn,
                                                short* __restrict__ kn) {
  int wave = threadIdx.x >> 6, lane = threadIdx.x & 63;
  int l = blockIdx.x * 4 + wave;
  int h = blockIdx.y;
  int isK = blockIdx.z;
  const float* src = (isK ? kraw : qraw) + ((size_t)h * LQ + l) * DHEADC;
  const float* sc  = isK ? k_scale : q_scale;
  short* dst = (isK ? kn : qn) + ((size_t)h * LQ + l) * DHEADC;
  float2 tv = *(const float2*)(src + lane * 2);
  float ssq = tv.x * tv.x + tv.y * tv.y;
#pragma unroll
  for (int m = 1; m < 64; m <<= 1) ssq += __shfl_xor(ssq, m);
  float rr = rsqrtf(ssq * (1.0f / 128.0f) + EPSV);
  float t0 = tv.x * rr * sc[lane * 2];
  float t1 = tv.y * rr * sc[lane * 2 + 1];
  float4 p4 = *(const float4*)(pe + ((size_t)l * 64 + lane) * 4);
  float o0 = p4.x * t0 + p4.y * t1;
  float o1 = p4.z * t0 + p4.w * t1;
  if (!isK) { o0 *= 0.08838834764831845f; o1 *= 0.08838834764831845f; }  // 1/sqrt(128)
  dst[lane * 2] = f2bf(o0);
  dst[lane * 2 + 1] = f2bf(o1);
}

// ---------------- Flash attention: block = (head, 128 q rows) ----------------
__global__ __launch_bounds__(256) void k_flash(const short* __restrict__ qn,
                                               const short* __restrict__ kn,
                                               const short* __restrict__ vt,
                                               short* __restrict__ a2) {
  __shared__ short Qs[128][136];
  __shared__ short Ks[32][136];
  __shared__ short Vs[128][40];
  __shared__ short Ps[4][32][40];
  int t = threadIdx.x;
  int qb = blockIdx.x * 128, h = blockIdx.y;
  int wave = t >> 6, lane = t & 63;
  int lrow = lane & 15, lko = (lane >> 4) * 8;
  int wm = wave * 32;
  const short* qbase = qn + ((size_t)h * LQ + qb) * DHEADC;
#pragma unroll
  for (int i = 0; i < 8; i++) {
    int idx = i * 256 + t;
    int row = idx >> 4, c = (idx & 15) * 8;
    *(short8*)&Qs[row][c] = *(const short8*)(qbase + (size_t)row * DHEADC + c);
  }
  f32x4 zero = {0.f, 0.f, 0.f, 0.f};
  f32x4 oacc[2][8];
#pragma unroll
  for (int i = 0; i < 2; i++)
#pragma unroll
    for (int j = 0; j < 8; j++) oacc[i][j] = zero;
  float mI[2][4], lI[2][4];
#pragma unroll
  for (int i = 0; i < 2; i++)
#pragma unroll
    for (int r = 0; r < 4; r++) { mI[i][r] = -1e30f; lI[i][r] = 0.f; }
  __syncthreads();
  for (int kt = 0; kt < 64; kt++) {
    int krow0 = kt * 32;
#pragma unroll
    for (int i = 0; i < 2; i++) {
      int idx = i * 256 + t;
      int row = idx >> 4, c = (idx & 15) * 8;
      *(short8*)&Ks[row][c] = *(const short8*)(kn + ((size_t)h * LQ + krow0 + row) * DHEADC + c);
    }
#pragma unroll
    for (int i = 0; i < 2; i++) {
      int idx = i * 256 + t;
      int d = idx >> 2, c = (idx & 3) * 8;
      *(short8*)&Vs[d][c] = *(const short8*)(vt + ((size_t)h * DHEADC + d) * LQ + krow0 + c);
    }
    __syncthreads();
    f32x4 sacc[2][2];
#pragma unroll
    for (int i = 0; i < 2; i++)
#pragma unroll
      for (int j = 0; j < 2; j++) sacc[i][j] = zero;
#pragma unroll
    for (int kk = 0; kk < 4; kk++) {
      short8 qa[2], kb[2];
#pragma unroll
      for (int i = 0; i < 2; i++) qa[i] = *(const short8*)&Qs[wm + i * 16 + lrow][kk * 32 + lko];
#pragma unroll
      for (int j = 0; j < 2; j++) kb[j] = *(const short8*)&Ks[j * 16 + lrow][kk * 32 + lko];
#pragma unroll
      for (int i = 0; i < 2; i++)
#pragma unroll
        for (int j = 0; j < 2; j++)
          sacc[i][j] = __builtin_amdgcn_mfma_f32_16x16x32_bf16(qa[i], kb[j], sacc[i][j], 0, 0, 0);
    }
    // online softmax (rows live in (lane>>4, reg); reduce across lane&15)
#pragma unroll
    for (int i = 0; i < 2; i++) {
      float al[4];
#pragma unroll
      for (int r = 0; r < 4; r++) {
        float mx = fmaxf(sacc[i][0][r], sacc[i][1][r]);
#pragma unroll
        for (int m = 1; m < 16; m <<= 1) mx = fmaxf(mx, __shfl_xor(mx, m));
        float mnew = fmaxf(mI[i][r], mx);
        float alpha = exp2f((mI[i][r] - mnew) * 1.4426950408889634f);
        float p0 = exp2f((sacc[i][0][r] - mnew) * 1.4426950408889634f);
        float p1 = exp2f((sacc[i][1][r] - mnew) * 1.4426950408889634f);
        sacc[i][0][r] = p0; sacc[i][1][r] = p1;
        float rs = p0 + p1;
#pragma unroll
        for (int m = 1; m < 16; m <<= 1) rs += __shfl_xor(rs, m);
        lI[i][r] = lI[i][r] * alpha + rs;
        mI[i][r] = mnew;
        al[r] = alpha;
      }
#pragma unroll
      for (int j = 0; j < 8; j++) {
        f32x4 o = oacc[i][j];
        o[0] *= al[0]; o[1] *= al[1]; o[2] *= al[2]; o[3] *= al[3];
        oacc[i][j] = o;
      }
      // P: C/D layout -> LDS (transpose to A-operand layout)
#pragma unroll
      for (int j = 0; j < 2; j++)
#pragma unroll
        for (int r = 0; r < 4; r++)
          Ps[wave][i * 16 + (lane >> 4) * 4 + r][j * 16 + lrow] = f2bf(sacc[i][j][r]);
    }
    short8 pa[2];
#pragma unroll
    for (int i = 0; i < 2; i++) pa[i] = *(const short8*)&Ps[wave][i * 16 + lrow][lko];
#pragma unroll
    for (int j = 0; j < 8; j++) {
      short8 vb = *(const short8*)&Vs[j * 16 + lrow][lko];
#pragma unroll
      for (int i = 0; i < 2; i++)
        oacc[i][j] = __builtin_amdgcn_mfma_f32_16x16x32_bf16(pa[i], vb, oacc[i][j], 0, 0, 0);
    }
    __syncthreads();
  }
#pragma unroll
  for (int i = 0; i < 2; i++) {
    float inv[4];
#pragma unroll
    for (int r = 0; r < 4; r++) inv[r] = 1.0f / lI[i][r];
#pragma unroll
    for (int j = 0; j < 8; j++) {
#pragma unroll
      for (int r = 0; r < 4; r++) {
        int row = qb + wm + i * 16 + (lane >> 4) * 4 + r;
        int col = h * DHEADC + j * 16 + lrow;
        a2[(size_t)row * KIN2 + col] = f2bf(oacc[i][j][r] * inv[r]);
      }
    }
  }
}

// ---------------- GEMM2: a2(2048x15360) @ W2t(3072x15360)^T, fused residual ----------------
__global__ __launch_bounds__(256) void k_gemm2(const short* __restrict__ A,
                                               const short* __restrict__ Bt,
                                               const float* __restrict__ bias,
                                               const float* __restrict__ x,
                                               const float* __restrict__ gate,
                                               float* __restrict__ out) {
  __shared__ __align__(16) short As[128 * 32];
  __shared__ __align__(16) short Bs[128 * 32];
  const int K = KIN2;
  int t = threadIdx.x;
  int bm = blockIdx.x * 128, bn = blockIdx.y * 128;
  int wave = t >> 6, lane = t & 63;
  int wm = (wave >> 1) * 64, wn = (wave & 1) * 64;
  int lrow = lane & 15, lko = (lane >> 4) * 8;
  int srow = wave * 16 + (lane >> 2);
  int scol = (lane & 3) * 8;
  const short* ga0 = A + (size_t)(bm + srow) * K + scol;
  const short* ga1 = ga0 + (size_t)64 * K;
  const short* gb0 = Bt + (size_t)(bn + srow) * K + scol;
  const short* gb1 = gb0 + (size_t)64 * K;
  short* la0 = As + wave * 512;
  short* la1 = As + 64 * 32 + wave * 512;
  short* lb0 = Bs + wave * 512;
  short* lb1 = Bs + 64 * 32 + wave * 512;
  f32x4 zero = {0.f, 0.f, 0.f, 0.f};
  f32x4 acc[4][4];
#pragma unroll
  for (int i = 0; i < 4; i++)
#pragma unroll
    for (int j = 0; j < 4; j++) acc[i][j] = zero;
  for (int k0 = 0; k0 < K; k0 += 32) {
    __syncthreads();
    async_ld16(la0, ga0 + k0);
    async_ld16(la1, ga1 + k0);
    async_ld16(lb0, gb0 + k0);
    async_ld16(lb1, gb1 + k0);
    __syncthreads();
    short8 af[4], bfr[4];
#pragma unroll
    for (int i = 0; i < 4; i++) af[i] = *(const short8*)&As[(wm + i * 16 + lrow) * 32 + lko];
#pragma unroll
    for (int j = 0; j < 4; j++) bfr[j] = *(const short8*)&Bs[(wn + j * 16 + lrow) * 32 + lko];
#pragma unroll
    for (int i = 0; i < 4; i++)
#pragma unroll
      for (int j = 0; j < 4; j++)
        acc[i][j] = __builtin_amdgcn_mfma_f32_16x16x32_bf16(af[i], bfr[j], acc[i][j], 0, 0, 0);
  }
  int r0 = bm + wm + ((lane >> 4) << 2);
  int c0 = bn + wn + lrow;
#pragma unroll
  for (int j = 0; j < 4; j++) {
    int col = c0 + j * 16;
    float bb = bias[col];
    float g = gate[col];
#pragma unroll
    for (int i = 0; i < 4; i++) {
#pragma unroll
      for (int r = 0; r < 4; r++) {
        int row = r0 + i * 16 + r;
        float v = acc[i][j][r] + bb;
        out[(size_t)row * DMODEL + col] = x[(size_t)row * DMODEL + col] + g * v;
      }
    }
  }
}

extern "C" void kernel_launch(void* const* d_in, const int* in_sizes, int n_in,
                              void* d_out, int out_size, void* d_ws, size_t ws_size,
                              hipStream_t stream) {
  (void)in_sizes; (void)n_in; (void)out_size; (void)ws_size;
  const float* x       = (const float*)d_in[0];
  const float* vec     = (const float*)d_in[1];
  const float* pe      = (const float*)d_in[2];
  const float* mod_w   = (const float*)d_in[3];
  const float* mod_b   = (const float*)d_in[4];
  const float* lin1_w  = (const float*)d_in[5];
  const float* lin1_b  = (const float*)d_in[6];
  const float* lin2_w  = (const float*)d_in[7];
  const float* lin2_b  = (const float*)d_in[8];
  const float* q_scale = (const float*)d_in[9];
  const float* k_scale = (const float*)d_in[10];
  float* out = (float*)d_out;

  char* base = (char*)d_ws;
  size_t off = 0;
  auto carve = [&](size_t bytes) -> void* {
    void* q = base + off;
    off += (bytes + 255) & ~(size_t)255;
    return q;
  };
  short* W1t  = (short*)carve((size_t)NOUT1 * DMODEL * 2);      // also W2t later
  short* xmod = (short*)carve((size_t)LQ * DMODEL * 2);
  float* qraw = (float*)carve((size_t)NHEADS * LQ * DHEADC * 4);
  float* kraw = (float*)carve((size_t)NHEADS * LQ * DHEADC * 4);
  short* qnb  = (short*)carve((size_t)NHEADS * LQ * DHEADC * 2);
  short* knb  = (short*)carve((size_t)NHEADS * LQ * DHEADC * 2);
  short* vtb  = (short*)carve((size_t)NHEADS * LQ * DHEADC * 2);
  short* a2   = (short*)carve((size_t)LQ * KIN2 * 2);
  float* modv = (float*)carve((size_t)NQKV * 4);
  float* part = (float*)carve((size_t)24 * NQKV * 4);

  k_wconv<<<dim3(DMODEL / 32, NOUT1 / 32), 256, 0, stream>>>(lin1_w, W1t, DMODEL, NOUT1);
  k_modpart<<<dim3(NQKV / 256, 24), 256, 0, stream>>>(vec, mod_w, part);
  k_modred<<<NQKV / 256, 256, 0, stream>>>(part, mod_b, modv);
  k_ln<<<LQ, 256, 0, stream>>>(x, modv, xmod);
  k_gemm1<<<dim3(LQ / 128, NOUT1 / 128), 256, 0, stream>>>(xmod, W1t, lin1_b, qraw, kraw, vtb, a2);
  k_wconv<<<dim3(KIN2 / 32, DMODEL / 32), 256, 0, stream>>>(lin2_w, W1t, KIN2, DMODEL);
  k_qkprep<<<dim3(LQ / 4, NHEADS, 2), 256, 0, stream>>>(qraw, kraw, pe, q_scale, k_scale, qnb, knb);
  k_flash<<<dim3(LQ / 128, NHEADS), 256, 0, stream>>>(qnb, knb, vtb, a2);
  k_gemm2<<<dim3(LQ / 128, DMODEL / 128), 256, 0, stream>>>(a2, W1t, lin2_b, x, modv + 2 * DMODEL, out);
}